// Round 3
// baseline (11874.593 us; speedup 1.0000x reference)
//
#include <hip/hip_runtime.h>

typedef unsigned short u16;
typedef unsigned int   u32;
typedef unsigned long long u64;
typedef __attribute__((ext_vector_type(8))) short bf16x8;
typedef __attribute__((ext_vector_type(4))) float f32x4;

// ---------- helpers ----------
__device__ __forceinline__ u16 f2bf(float f) {
    u32 u; __builtin_memcpy(&u, &f, 4);
    u32 r = (u + 0x7FFFu + ((u >> 16) & 1u)) >> 16;   // RTNE
    return (u16)r;
}
__device__ __forceinline__ float bf2f(u16 h) {
    u32 u = ((u32)h) << 16; float f; __builtin_memcpy(&f, &u, 4); return f;
}
__device__ __forceinline__ float sigmoidf(float x) { return 1.f / (1.f + __expf(-x)); }
__device__ __forceinline__ float tanh_safe(float x) {
    float e = __expf(-2.f * fabsf(x));
    float t = (1.f - e) / (1.f + e);
    return x >= 0.f ? t : -t;
}

// ---------- fp32 -> bf16 hi/lo split ----------
__global__ __launch_bounds__(256) void castk2(const float* __restrict__ s, u16* __restrict__ hi,
                                              u16* __restrict__ lo, int n) {
    int i = blockIdx.x * 256 + threadIdx.x;
    if (i < n) {
        float f = s[i];
        u16 h = f2bf(f);
        hi[i] = h;
        lo[i] = f2bf(f - bf2f(h));
    }
}

// ---------- embedding gather + cast ----------
__global__ __launch_bounds__(256) void embed_cast(const int* __restrict__ x, const float* __restrict__ emb,
                                                  u16* __restrict__ x0) {
    int m = blockIdx.x;
    int idx = x[m];
    const float2* src = (const float2*)(emb + (size_t)idx * 512);
    u16* dst = x0 + (size_t)m * 512;
    int t = threadIdx.x;
    float2 v = src[t];
    dst[t * 2]     = f2bf(v.x);
    dst[t * 2 + 1] = f2bf(v.y);
}

// ---------- C[M,N] = A[M,K] @ (Bhi+Blo)[N,K]^T ----------
__global__ __launch_bounds__(256) void gemm_bt(const u16* __restrict__ A, const u16* __restrict__ Bhi,
                                               const u16* __restrict__ Blo,
                                               u16* __restrict__ C, int M, int N, int K) {
    __shared__ __align__(16) u16 sA[128 * 32];
    __shared__ __align__(16) u16 sBh[128 * 32];
    __shared__ __align__(16) u16 sBl[128 * 32];
    const int tid  = threadIdx.x;
    const int lane = tid & 63, wave = tid >> 6;
    const int m0 = blockIdx.y * 128, n0 = blockIdx.x * 128;
    const int wm = (wave >> 1) * 64, wn = (wave & 1) * 64;
    f32x4 acc[4][4] = {};

    const int r0 = tid >> 2, c8 = (tid & 3) * 8;
    const int r1 = r0 + 64;
    const u16* Ap   = A   + (size_t)(m0 + r0) * K + c8;
    const u16* Ap2  = A   + (size_t)(m0 + r1) * K + c8;
    const u16* Bhp  = Bhi + (size_t)(n0 + r0) * K + c8;
    const u16* Bhp2 = Bhi + (size_t)(n0 + r1) * K + c8;
    const u16* Blp  = Blo + (size_t)(n0 + r0) * K + c8;
    const u16* Blp2 = Blo + (size_t)(n0 + r1) * K + c8;

    uint4 ra0, ra1, rh0, rh1, rl0, rl1;
    ra0 = *(const uint4*)(Ap);   ra1 = *(const uint4*)(Ap2);
    rh0 = *(const uint4*)(Bhp);  rh1 = *(const uint4*)(Bhp2);
    rl0 = *(const uint4*)(Blp);  rl1 = *(const uint4*)(Blp2);

    for (int kk = 0; kk < K; kk += 32) {
        __syncthreads();
        *(uint4*)(sA  + tid * 8)        = ra0;
        *(uint4*)(sA  + 2048 + tid * 8) = ra1;
        *(uint4*)(sBh + tid * 8)        = rh0;
        *(uint4*)(sBh + 2048 + tid * 8) = rh1;
        *(uint4*)(sBl + tid * 8)        = rl0;
        *(uint4*)(sBl + 2048 + tid * 8) = rl1;
        int kn = kk + 32;
        if (kn < K) {
            ra0 = *(const uint4*)(Ap + kn);   ra1 = *(const uint4*)(Ap2 + kn);
            rh0 = *(const uint4*)(Bhp + kn);  rh1 = *(const uint4*)(Bhp2 + kn);
            rl0 = *(const uint4*)(Blp + kn);  rl1 = *(const uint4*)(Blp2 + kn);
        }
        __syncthreads();
        bf16x8 av[4], bh[4], bl[4];
#pragma unroll
        for (int i = 0; i < 4; ++i) {
            av[i] = *(const bf16x8*)(sA  + (wm + i * 16 + (lane & 15)) * 32 + (lane >> 4) * 8);
            bh[i] = *(const bf16x8*)(sBh + (wn + i * 16 + (lane & 15)) * 32 + (lane >> 4) * 8);
            bl[i] = *(const bf16x8*)(sBl + (wn + i * 16 + (lane & 15)) * 32 + (lane >> 4) * 8);
        }
#pragma unroll
        for (int i = 0; i < 4; ++i)
#pragma unroll
            for (int j = 0; j < 4; ++j) {
                acc[i][j] = __builtin_amdgcn_mfma_f32_16x16x32_bf16(av[i], bh[j], acc[i][j], 0, 0, 0);
                acc[i][j] = __builtin_amdgcn_mfma_f32_16x16x32_bf16(av[i], bl[j], acc[i][j], 0, 0, 0);
            }
    }
#pragma unroll
    for (int i = 0; i < 4; ++i) {
        int m = m0 + wm + i * 16 + ((lane >> 4) << 2);
#pragma unroll
        for (int j = 0; j < 4; ++j) {
            int n = n0 + wn + j * 16 + (lane & 15);
#pragma unroll
            for (int rr = 0; rr < 4; ++rr)
                C[(size_t)(m + rr) * N + n] = f2bf(acc[i][j][rr]);
        }
    }
}

// ---------- persistent bidirectional LSTM recurrence ----------
// grid = 128 blocks: dir = blockIdx>>6, slice = blockIdx&63 -> hidden units [slice*8, slice*8+8)
// Whh-hi fragments in VGPRs; Whh-lo plane in LDS (guaranteed residency).
// Sync: per-slice release flags (parallel stores), wave-0 polls all 64 via wave-wide acquire load.
template <int LAYER>
__global__ __launch_bounds__(256, 1) void lstm_rec(
    const u16* __restrict__ xp_f, const u16* __restrict__ xp_b,
    const u16* __restrict__ whh_f_hi, const u16* __restrict__ whh_f_lo,
    const u16* __restrict__ whh_b_hi, const u16* __restrict__ whh_b_lo,
    const float* __restrict__ bih_f, const float* __restrict__ bhh_f,
    const float* __restrict__ bih_b, const float* __restrict__ bhh_b,
    u16* __restrict__ out0, float* __restrict__ pooled, const int* __restrict__ mask,
    u16* hbuf, u32* flags)
{
    const int HP = 520;                              // padded LDS row (u16 units)
    __shared__ __align__(16) u16  sHhi[32 * 520];    // 33.3 KB
    __shared__ __align__(16) u16  sHlo[32 * 520];    // 33.3 KB
    __shared__ __align__(16) u16  sWlo[32 * 520];    // lo-weights [col][k], 33.3 KB
    __shared__ __align__(16) u16  sXp[32 * 32];
    __shared__ __align__(16) float sG[32 * 33];
    __shared__ __align__(16) u16  sHoutHi[32 * 8];
    __shared__ __align__(16) u16  sHoutLo[32 * 8];

    const int tid = threadIdx.x;
    const int dir = blockIdx.x >> 6;
    const int slice = blockIdx.x & 63;
    const u16* xp     = dir ? xp_b : xp_f;
    const u16* whhH   = dir ? whh_b_hi : whh_f_hi;
    const u16* whhL   = dir ? whh_b_lo : whh_f_lo;
    const float* bih  = dir ? bih_b : bih_f;
    const float* bhh  = dir ? bhh_b : bhh_f;
    u16* hbD = hbuf + dir * 65536;            // 2 bufs x 2 planes x 32*512 u16
    u32* myFlags = flags + dir * 256;         // 64 slices x 16B stride

    const int wave = tid >> 6, lane = tid & 63;
    const int wm = (wave >> 1) * 16;          // batch half
    const int wn = (wave & 1) * 16;           // gate-col half

    // hi-weight B-fragments resident in VGPRs (16 x bf16x8 = 64 VGPRs)
    bf16x8 wfragH[16];
    {
        int n = wn + (lane & 15);
        int q = n >> 3, rr = n & 7;
        const u16* wrh = whhH + (size_t)(q * 512 + slice * 8 + rr) * 512 + (lane >> 4) * 8;
#pragma unroll
        for (int k2 = 0; k2 < 16; ++k2) wfragH[k2] = *(const bf16x8*)(wrh + k2 * 32);
    }
    // lo-weight plane into LDS: col c (0..31) -> global gate row (c>>3)*512 + slice*8 + (c&7)
    {
        int c = tid >> 3;
        int grow = (c >> 3) * 512 + slice * 8 + (c & 7);
        const u16* src = whhL + (size_t)grow * 512;
        u16* dst = sWlo + c * HP;
#pragma unroll
        for (int jj = 0; jj < 8; ++jj) {
            int ch = (tid & 7) + 8 * jj;
            *(uint4*)(dst + ch * 8) = *(const uint4*)(src + ch * 8);
        }
    }

    const int b = tid >> 3, r = tid & 7;      // cell-phase mapping
    float bias[4];
#pragma unroll
    for (int q = 0; q < 4; ++q) {
        int g = q * 512 + slice * 8 + r;
        bias[q] = bih[g] + bhh[g];
    }
    float cstate = 0.f, pool = 0.f;
    const int aoff = (wm + (lane & 15)) * HP + (lane >> 4) * 8;
    const int boff = (wn + (lane & 15)) * HP + (lane >> 4) * 8;   // sWlo frag
    const int gRow = wm + ((lane >> 4) << 2), gCol = wn + (lane & 15);
    const int srow = tid >> 3, sc = tid & 7;  // staging: row, 128B-chunk id
    __syncthreads();

    for (int t = 0; t < 512; ++t) {
        const int tt = dir ? (511 - t) : t;
        // 1. stage xp tile (issue early; latency hidden under flag poll)
        if (tid < 128) {
            int xb = tid >> 2, xq = tid & 3;
            const uint4 v = *(const uint4*)(xp + ((size_t)(xb * 512 + tt)) * 2048 + xq * 512 + slice * 8);
            *(uint4*)(sXp + xb * 32 + xq * 8) = v;
        }
        if (t > 0) {
            // 2. wave 0 polls all 64 slice flags with one wave-wide acquire load
            if (tid < 64) {
                const u32* fp = myFlags + tid * 4;
                for (;;) {
                    u32 v = __hip_atomic_load(fp, __ATOMIC_ACQUIRE, __HIP_MEMORY_SCOPE_AGENT);
                    if (__all((int)(v >= (u32)t))) break;
                    __builtin_amdgcn_s_sleep(1);
                }
            }
            __syncthreads();
            // 3. stage h hi/lo: batch ALL 32 atomic loads into regs, then LDS writes
            {
                const u16* hp = hbD + ((t - 1) & 1) * 32768 + srow * 512 + sc * 64;  // 128B chunk
                const u16* lp = hp + 16384;
                u64 rh[16], rl[16];
#pragma unroll
                for (int j = 0; j < 16; ++j)
                    rh[j] = __hip_atomic_load((const u64*)hp + j, __ATOMIC_RELAXED, __HIP_MEMORY_SCOPE_AGENT);
#pragma unroll
                for (int j = 0; j < 16; ++j)
                    rl[j] = __hip_atomic_load((const u64*)lp + j, __ATOMIC_RELAXED, __HIP_MEMORY_SCOPE_AGENT);
                u16* dhi = sHhi + srow * HP + sc * 64;
                u16* dlo = sHlo + srow * HP + sc * 64;
#pragma unroll
                for (int j = 0; j < 8; ++j) {
                    uint4 vh; __builtin_memcpy(&vh, &rh[j * 2], 16);
                    uint4 vl; __builtin_memcpy(&vl, &rl[j * 2], 16);
                    *(uint4*)(dhi + j * 8) = vh;
                    *(uint4*)(dlo + j * 8) = vl;
                }
            }
        }
        __syncthreads();
        // 4. G = h @ Whh_slice^T with hi/lo split (skip t=0: h0=0)
        f32x4 acc = {};
        if (t > 0) {
#pragma unroll
            for (int k2 = 0; k2 < 16; ++k2) {
                bf16x8 ah = *(const bf16x8*)(sHhi + aoff + k2 * 32);
                bf16x8 al = *(const bf16x8*)(sHlo + aoff + k2 * 32);
                bf16x8 bl = *(const bf16x8*)(sWlo + boff + k2 * 32);
                acc = __builtin_amdgcn_mfma_f32_16x16x32_bf16(ah, wfragH[k2], acc, 0, 0, 0);
                acc = __builtin_amdgcn_mfma_f32_16x16x32_bf16(al, wfragH[k2], acc, 0, 0, 0);
                acc = __builtin_amdgcn_mfma_f32_16x16x32_bf16(ah, bl,         acc, 0, 0, 0);
            }
        }
#pragma unroll
        for (int rr = 0; rr < 4; ++rr) sG[(gRow + rr) * 33 + gCol] = acc[rr];
        __syncthreads();
        // 5. LSTM cell (fp32)
        {
            float gq[4];
#pragma unroll
            for (int q = 0; q < 4; ++q)
                gq[q] = sG[b * 33 + q * 8 + r] + bf2f(sXp[b * 32 + q * 8 + r]) + bias[q];
            float ig = sigmoidf(gq[0]), fg = sigmoidf(gq[1]);
            float gg = tanh_safe(gq[2]), og = sigmoidf(gq[3]);
            cstate = fg * cstate + ig * gg;
            float h = og * tanh_safe(cstate);
            u16 hh = f2bf(h);
            if (LAYER == 0) {
                out0[((size_t)(b * 512 + tt)) * 1024 + dir * 512 + slice * 8 + r] = hh;
            } else {
                pool += h * (float)mask[b * 512 + tt];
            }
            sHoutHi[b * 8 + r] = hh;
            sHoutLo[b * 8 + r] = f2bf(h - bf2f(hh));
        }
        __syncthreads();
        // 6. publish h slice (u64 stores, both planes)
        if (tid < 128) {
            int plane = tid >> 6;
            int w = tid & 63, row = w >> 1, half = w & 1;
            u64 v = plane ? ((const u64*)sHoutLo)[w] : ((const u64*)sHoutHi)[w];
            u64* g = (u64*)(hbD + (t & 1) * 32768 + plane * 16384 + row * 512 + slice * 8) + half;
            __hip_atomic_store(g, v, __ATOMIC_RELAXED, __HIP_MEMORY_SCOPE_AGENT);
        }
        __syncthreads();   // drains vmcnt in publishing waves -> stores visible
        if (tid == 0)
            __hip_atomic_store(myFlags + slice * 4, (u32)(t + 1), __ATOMIC_RELEASE, __HIP_MEMORY_SCOPE_AGENT);
    }
    if (LAYER == 1)
        pooled[(size_t)b * 1024 + dir * 512 + slice * 8 + r] = pool;
}

// ---------- final: logits = (pooled/msum) @ fcW^T + fcb ----------
__global__ __launch_bounds__(256) void final_fc(const float* __restrict__ pooled, const int* __restrict__ mask,
                                                const float* __restrict__ fcW, const float* __restrict__ fcb,
                                                float* __restrict__ out) {
    __shared__ float red[256];
    int tid = threadIdx.x;
    int pair = tid & 63, kc = tid >> 6;
    int b = pair >> 1, c = pair & 1;
    float s = 0.f;
    for (int k = kc * 256; k < kc * 256 + 256; ++k)
        s += pooled[b * 1024 + k] * fcW[c * 1024 + k];
    red[tid] = s;
    __syncthreads();
    if (kc == 0) {
        float tot = red[pair] + red[64 + pair] + red[128 + pair] + red[192 + pair];
        float ms = 0.f;
        for (int t = 0; t < 512; ++t) ms += (float)mask[b * 512 + t];
        ms = fmaxf(ms, 1e-9f);
        out[b * 2 + c] = tot / ms + fcb[c];
    }
}

extern "C" void kernel_launch(void* const* d_in, const int* in_sizes, int n_in,
                              void* d_out, int out_size, void* d_ws, size_t ws_size,
                              hipStream_t stream) {
    (void)in_sizes; (void)n_in; (void)out_size; (void)ws_size;
    const int*   x     = (const int*)d_in[0];
    const int*   amask = (const int*)d_in[1];
    const float* emb   = (const float*)d_in[2];
    const float* fcW   = (const float*)d_in[3];
    const float* fcb   = (const float*)d_in[4];
    const float* fWih0 = (const float*)d_in[5];
    const float* fWhh0 = (const float*)d_in[6];
    const float* fbih0 = (const float*)d_in[7];
    const float* fbhh0 = (const float*)d_in[8];
    const float* bWih0 = (const float*)d_in[9];
    const float* bWhh0 = (const float*)d_in[10];
    const float* bbih0 = (const float*)d_in[11];
    const float* bbhh0 = (const float*)d_in[12];
    const float* fWih1 = (const float*)d_in[13];
    const float* fWhh1 = (const float*)d_in[14];
    const float* fbih1 = (const float*)d_in[15];
    const float* fbhh1 = (const float*)d_in[16];
    const float* bWih1 = (const float*)d_in[17];
    const float* bWhh1 = (const float*)d_in[18];
    const float* bbih1 = (const float*)d_in[19];
    const float* bbhh1 = (const float*)d_in[20];

    char* ws = (char*)d_ws;
    size_t off = 0;
    auto alloc = [&](size_t bytes) { void* p = ws + off; off += (bytes + 1023) & ~(size_t)1023; return p; };
    u16* x0    = (u16*)alloc((size_t)16384 * 512 * 2);
    u16* xpf   = (u16*)alloc((size_t)16384 * 2048 * 2);
    u16* xpb   = (u16*)alloc((size_t)16384 * 2048 * 2);
    u16* out0  = (u16*)alloc((size_t)16384 * 1024 * 2);
    u16* wih0fH = (u16*)alloc((size_t)2048 * 512 * 2);
    u16* wih0fL = (u16*)alloc((size_t)2048 * 512 * 2);
    u16* wih0bH = (u16*)alloc((size_t)2048 * 512 * 2);
    u16* wih0bL = (u16*)alloc((size_t)2048 * 512 * 2);
    u16* whh0fH = (u16*)alloc((size_t)2048 * 512 * 2);
    u16* whh0fL = (u16*)alloc((size_t)2048 * 512 * 2);
    u16* whh0bH = (u16*)alloc((size_t)2048 * 512 * 2);
    u16* whh0bL = (u16*)alloc((size_t)2048 * 512 * 2);
    u16* wih1fH = (u16*)alloc((size_t)2048 * 1024 * 2);
    u16* wih1fL = (u16*)alloc((size_t)2048 * 1024 * 2);
    u16* wih1bH = (u16*)alloc((size_t)2048 * 1024 * 2);
    u16* wih1bL = (u16*)alloc((size_t)2048 * 1024 * 2);
    u16* whh1fH = (u16*)alloc((size_t)2048 * 512 * 2);
    u16* whh1fL = (u16*)alloc((size_t)2048 * 512 * 2);
    u16* whh1bH = (u16*)alloc((size_t)2048 * 512 * 2);
    u16* whh1bL = (u16*)alloc((size_t)2048 * 512 * 2);
    float* pooled = (float*)alloc((size_t)32 * 1024 * 4);
    u16* hbuf  = (u16*)alloc((size_t)2 * 2 * 2 * 32 * 512 * 2);
    u32* flg   = (u32*)alloc(8192);

    hipMemsetAsync(flg, 0, 8192, stream);

    const int NW0 = 2048 * 512, NW1 = 2048 * 1024;
    castk2<<<dim3((NW0 + 255) / 256), 256, 0, stream>>>(fWih0, wih0fH, wih0fL, NW0);
    castk2<<<dim3((NW0 + 255) / 256), 256, 0, stream>>>(bWih0, wih0bH, wih0bL, NW0);
    castk2<<<dim3((NW0 + 255) / 256), 256, 0, stream>>>(fWhh0, whh0fH, whh0fL, NW0);
    castk2<<<dim3((NW0 + 255) / 256), 256, 0, stream>>>(bWhh0, whh0bH, whh0bL, NW0);
    castk2<<<dim3((NW1 + 255) / 256), 256, 0, stream>>>(fWih1, wih1fH, wih1fL, NW1);
    castk2<<<dim3((NW1 + 255) / 256), 256, 0, stream>>>(bWih1, wih1bH, wih1bL, NW1);
    castk2<<<dim3((NW0 + 255) / 256), 256, 0, stream>>>(fWhh1, whh1fH, whh1fL, NW0);
    castk2<<<dim3((NW0 + 255) / 256), 256, 0, stream>>>(bWhh1, whh1bH, whh1bL, NW0);

    embed_cast<<<dim3(16384), 256, 0, stream>>>(x, emb, x0);

    gemm_bt<<<dim3(16, 128), 256, 0, stream>>>(x0, wih0fH, wih0fL, xpf, 16384, 2048, 512);
    gemm_bt<<<dim3(16, 128), 256, 0, stream>>>(x0, wih0bH, wih0bL, xpb, 16384, 2048, 512);
    lstm_rec<0><<<dim3(128), 256, 0, stream>>>(xpf, xpb, whh0fH, whh0fL, whh0bH, whh0bL,
                                               fbih0, fbhh0, bbih0, bbhh0,
                                               out0, nullptr, nullptr, hbuf, flg);
    gemm_bt<<<dim3(16, 128), 256, 0, stream>>>(out0, wih1fH, wih1fL, xpf, 16384, 2048, 1024);
    gemm_bt<<<dim3(16, 128), 256, 0, stream>>>(out0, wih1bH, wih1bL, xpb, 16384, 2048, 1024);
    lstm_rec<1><<<dim3(128), 256, 0, stream>>>(xpf, xpb, whh1fH, whh1fL, whh1bH, whh1bL,
                                               fbih1, fbhh1, bbih1, bbhh1,
                                               nullptr, pooled, amask, hbuf, flg + 1024);

    final_fc<<<dim3(1), 256, 0, stream>>>(pooled, amask, fcW, fcb, (float*)d_out);
}

// Round 4
// 8254.955 us; speedup vs baseline: 1.4385x; 1.4385x over previous
//
#include <hip/hip_runtime.h>

typedef unsigned short u16;
typedef unsigned int   u32;
typedef unsigned long long u64;
typedef __attribute__((ext_vector_type(8))) short bf16x8;
typedef __attribute__((ext_vector_type(4))) float f32x4;

// ---------- helpers ----------
__device__ __forceinline__ u16 f2bf(float f) {
    u32 u; __builtin_memcpy(&u, &f, 4);
    u32 r = (u + 0x7FFFu + ((u >> 16) & 1u)) >> 16;   // RTNE
    return (u16)r;
}
__device__ __forceinline__ float bf2f(u16 h) {
    u32 u = ((u32)h) << 16; float f; __builtin_memcpy(&f, &u, 4); return f;
}
__device__ __forceinline__ float sigmoidf(float x) { return 1.f / (1.f + __expf(-x)); }
__device__ __forceinline__ float tanh_safe(float x) {
    float e = __expf(-2.f * fabsf(x));
    float t = (1.f - e) / (1.f + e);
    return x >= 0.f ? t : -t;
}

// ---------- fp32 -> bf16 hi/lo split ----------
__global__ __launch_bounds__(256) void castk2(const float* __restrict__ s, u16* __restrict__ hi,
                                              u16* __restrict__ lo, int n) {
    int i = blockIdx.x * 256 + threadIdx.x;
    if (i < n) {
        float f = s[i];
        u16 h = f2bf(f);
        hi[i] = h;
        lo[i] = f2bf(f - bf2f(h));
    }
}

// ---------- embedding gather + cast ----------
__global__ __launch_bounds__(256) void embed_cast(const int* __restrict__ x, const float* __restrict__ emb,
                                                  u16* __restrict__ x0) {
    int m = blockIdx.x;
    int idx = x[m];
    const float2* src = (const float2*)(emb + (size_t)idx * 512);
    u16* dst = x0 + (size_t)m * 512;
    int t = threadIdx.x;
    float2 v = src[t];
    dst[t * 2]     = f2bf(v.x);
    dst[t * 2 + 1] = f2bf(v.y);
}

// ---------- C[M,N] = A[M,K] @ (Bhi+Blo)[N,K]^T ----------
__global__ __launch_bounds__(256) void gemm_bt(const u16* __restrict__ A, const u16* __restrict__ Bhi,
                                               const u16* __restrict__ Blo,
                                               u16* __restrict__ C, int M, int N, int K) {
    __shared__ __align__(16) u16 sA[128 * 32];
    __shared__ __align__(16) u16 sBh[128 * 32];
    __shared__ __align__(16) u16 sBl[128 * 32];
    const int tid  = threadIdx.x;
    const int lane = tid & 63, wave = tid >> 6;
    const int m0 = blockIdx.y * 128, n0 = blockIdx.x * 128;
    const int wm = (wave >> 1) * 64, wn = (wave & 1) * 64;
    f32x4 acc[4][4] = {};

    const int r0 = tid >> 2, c8 = (tid & 3) * 8;
    const int r1 = r0 + 64;
    const u16* Ap   = A   + (size_t)(m0 + r0) * K + c8;
    const u16* Ap2  = A   + (size_t)(m0 + r1) * K + c8;
    const u16* Bhp  = Bhi + (size_t)(n0 + r0) * K + c8;
    const u16* Bhp2 = Bhi + (size_t)(n0 + r1) * K + c8;
    const u16* Blp  = Blo + (size_t)(n0 + r0) * K + c8;
    const u16* Blp2 = Blo + (size_t)(n0 + r1) * K + c8;

    uint4 ra0, ra1, rh0, rh1, rl0, rl1;
    ra0 = *(const uint4*)(Ap);   ra1 = *(const uint4*)(Ap2);
    rh0 = *(const uint4*)(Bhp);  rh1 = *(const uint4*)(Bhp2);
    rl0 = *(const uint4*)(Blp);  rl1 = *(const uint4*)(Blp2);

    for (int kk = 0; kk < K; kk += 32) {
        __syncthreads();
        *(uint4*)(sA  + tid * 8)        = ra0;
        *(uint4*)(sA  + 2048 + tid * 8) = ra1;
        *(uint4*)(sBh + tid * 8)        = rh0;
        *(uint4*)(sBh + 2048 + tid * 8) = rh1;
        *(uint4*)(sBl + tid * 8)        = rl0;
        *(uint4*)(sBl + 2048 + tid * 8) = rl1;
        int kn = kk + 32;
        if (kn < K) {
            ra0 = *(const uint4*)(Ap + kn);   ra1 = *(const uint4*)(Ap2 + kn);
            rh0 = *(const uint4*)(Bhp + kn);  rh1 = *(const uint4*)(Bhp2 + kn);
            rl0 = *(const uint4*)(Blp + kn);  rl1 = *(const uint4*)(Blp2 + kn);
        }
        __syncthreads();
        bf16x8 av[4], bh[4], bl[4];
#pragma unroll
        for (int i = 0; i < 4; ++i) {
            av[i] = *(const bf16x8*)(sA  + (wm + i * 16 + (lane & 15)) * 32 + (lane >> 4) * 8);
            bh[i] = *(const bf16x8*)(sBh + (wn + i * 16 + (lane & 15)) * 32 + (lane >> 4) * 8);
            bl[i] = *(const bf16x8*)(sBl + (wn + i * 16 + (lane & 15)) * 32 + (lane >> 4) * 8);
        }
#pragma unroll
        for (int i = 0; i < 4; ++i)
#pragma unroll
            for (int j = 0; j < 4; ++j) {
                acc[i][j] = __builtin_amdgcn_mfma_f32_16x16x32_bf16(av[i], bh[j], acc[i][j], 0, 0, 0);
                acc[i][j] = __builtin_amdgcn_mfma_f32_16x16x32_bf16(av[i], bl[j], acc[i][j], 0, 0, 0);
            }
    }
#pragma unroll
    for (int i = 0; i < 4; ++i) {
        int m = m0 + wm + i * 16 + ((lane >> 4) << 2);
#pragma unroll
        for (int j = 0; j < 4; ++j) {
            int n = n0 + wn + j * 16 + (lane & 15);
#pragma unroll
            for (int rr = 0; rr < 4; ++rr)
                C[(size_t)(m + rr) * N + n] = f2bf(acc[i][j][rr]);
        }
    }
}

// ---------- persistent bidirectional LSTM recurrence ----------
// grid = 128 blocks: dir = blockIdx>>6, slice = blockIdx&63 -> hidden units [slice*8, slice*8+8)
// No LDS roundtrip for h: MFMA A-fragments loaded DIRECTLY from IC h-buffer into registers
// (relaxed agent-scope u64 loads; compiler pipelines + fine-grained vmcnt before MFMAs).
// Waves split K: wave = (mtile = w&1, khalf = w>>1); partial G sums meet in sG[2] slots.
// Whh hi+lo fragments resident in registers/AGPRs (128 regs, constant over steps).
template <int LAYER>
__global__ __launch_bounds__(256, 1) void lstm_rec(
    const u16* __restrict__ xp_f, const u16* __restrict__ xp_b,
    const u16* __restrict__ whh_f_hi, const u16* __restrict__ whh_f_lo,
    const u16* __restrict__ whh_b_hi, const u16* __restrict__ whh_b_lo,
    const float* __restrict__ bih_f, const float* __restrict__ bhh_f,
    const float* __restrict__ bih_b, const float* __restrict__ bhh_b,
    u16* __restrict__ out0, float* __restrict__ pooled, const int* __restrict__ mask,
    u16* hbuf, u32* flags)
{
    __shared__ __align__(16) float sG[2][32][36];    // [khalf][batch][gatecol(pad 36)] -> <=2-way banks
    __shared__ __align__(16) u16  sXp[32][40];       // pad 40 -> <=2-way banks
    __shared__ __align__(16) u16  sHoutHi[32][8];
    __shared__ __align__(16) u16  sHoutLo[32][8];

    const int tid = threadIdx.x;
    const int dir = blockIdx.x >> 6;
    const int slice = blockIdx.x & 63;
    const u16* xp     = dir ? xp_b : xp_f;
    const u16* whhH   = dir ? whh_b_hi : whh_f_hi;
    const u16* whhL   = dir ? whh_b_lo : whh_f_lo;
    const float* bih  = dir ? bih_b : bih_f;
    const float* bhh  = dir ? bhh_b : bhh_f;
    u16* hbD = hbuf + dir * 65536;            // 2 bufs x 2 planes x [32][512] u16
    u32* myFlags = flags + dir * 64;          // 64 slices x 4B

    const int wave = tid >> 6, lane = tid & 63;
    const int mtile = wave & 1;               // batch 16-block
    const int khalf = wave >> 1;              // K half: [khalf*256, khalf*256+256)

    // Whh fragments: wH/wL[ntile][k2]; B-frag col n = ntile*16+(lane&15),
    // gate row = (col>>3)*512 + slice*8 + (col&7), k = khalf*256 + k2*32 + (lane>>4)*8
    bf16x8 wH[2][8], wL[2][8];
#pragma unroll
    for (int nt = 0; nt < 2; ++nt) {
        int col = nt * 16 + (lane & 15);
        size_t rowoff = (size_t)((col >> 3) * 512 + slice * 8 + (col & 7)) * 512
                        + khalf * 256 + (lane >> 4) * 8;
        const u16* ph = whhH + rowoff;
        const u16* pl = whhL + rowoff;
#pragma unroll
        for (int k2 = 0; k2 < 8; ++k2) {
            wH[nt][k2] = *(const bf16x8*)(ph + k2 * 32);
            wL[nt][k2] = *(const bf16x8*)(pl + k2 * 32);
        }
    }

    const int b = tid >> 3, r = tid & 7;      // cell-phase mapping
    float bias[4];
#pragma unroll
    for (int q = 0; q < 4; ++q) {
        int g = q * 512 + slice * 8 + r;
        bias[q] = bih[g] + bhh[g];
    }
    float cstate = 0.f, pool = 0.f;
    // A-frag base (u16 offset inside one plane): row = mtile*16+(lane&15), k-chunk = khalf*256+(lane>>4)*8
    const int afrag = (mtile * 16 + (lane & 15)) * 512 + khalf * 256 + (lane >> 4) * 8;
    const int gRow = mtile * 16 + ((lane >> 4) << 2), gCol0 = lane & 15;

    union HF { u64 q[2]; bf16x8 v; };

    for (int t = 0; t < 512; ++t) {
        const int tt = dir ? (511 - t) : t;
        // 1. stage xp tile (issue early; latency hidden under flag poll)
        if (tid < 128) {
            int xb = tid >> 2, xq = tid & 3;
            const uint4 v = *(const uint4*)(xp + ((size_t)(xb * 512 + tt)) * 2048 + xq * 512 + slice * 8);
            *(uint4*)(&sXp[xb][xq * 8]) = v;
        }
        f32x4 acc0 = {}, acc1 = {};
        if (t > 0) {
            // 2. wave 0: relaxed poll of all 64 slice flags (IC-mediated ordering; see publish)
            if (tid < 64) {
                const u32* fp = myFlags + tid;
                for (;;) {
                    u32 v = __hip_atomic_load(fp, __ATOMIC_RELAXED, __HIP_MEMORY_SCOPE_AGENT);
                    if (__all((int)(v >= (u32)t))) break;
                    __builtin_amdgcn_s_sleep(1);
                }
            }
            __syncthreads();
            // 3. load A-fragments (hi+lo) DIRECTLY from IC into registers; all 32 u64 loads pipeline
            const u16* hbase = hbD + ((t - 1) & 1) * 32768 + afrag;
            HF ah[8], al[8];
#pragma unroll
            for (int k2 = 0; k2 < 8; ++k2) {
                const u64* ph = (const u64*)(hbase + k2 * 32);
                const u64* pl = (const u64*)(hbase + 16384 + k2 * 32);
                ah[k2].q[0] = __hip_atomic_load(ph,     __ATOMIC_RELAXED, __HIP_MEMORY_SCOPE_AGENT);
                ah[k2].q[1] = __hip_atomic_load(ph + 1, __ATOMIC_RELAXED, __HIP_MEMORY_SCOPE_AGENT);
                al[k2].q[0] = __hip_atomic_load(pl,     __ATOMIC_RELAXED, __HIP_MEMORY_SCOPE_AGENT);
                al[k2].q[1] = __hip_atomic_load(pl + 1, __ATOMIC_RELAXED, __HIP_MEMORY_SCOPE_AGENT);
            }
            // 4. G partial sums (this wave's K half): 6 MFMAs per k2
#pragma unroll
            for (int k2 = 0; k2 < 8; ++k2) {
                acc0 = __builtin_amdgcn_mfma_f32_16x16x32_bf16(ah[k2].v, wH[0][k2], acc0, 0, 0, 0);
                acc1 = __builtin_amdgcn_mfma_f32_16x16x32_bf16(ah[k2].v, wH[1][k2], acc1, 0, 0, 0);
                acc0 = __builtin_amdgcn_mfma_f32_16x16x32_bf16(al[k2].v, wH[0][k2], acc0, 0, 0, 0);
                acc1 = __builtin_amdgcn_mfma_f32_16x16x32_bf16(al[k2].v, wH[1][k2], acc1, 0, 0, 0);
                acc0 = __builtin_amdgcn_mfma_f32_16x16x32_bf16(ah[k2].v, wL[0][k2], acc0, 0, 0, 0);
                acc1 = __builtin_amdgcn_mfma_f32_16x16x32_bf16(ah[k2].v, wL[1][k2], acc1, 0, 0, 0);
            }
        } else {
            __syncthreads();   // keep barrier count uniform-ish (cheap)
        }
#pragma unroll
        for (int rr = 0; rr < 4; ++rr) {
            sG[khalf][gRow + rr][gCol0]      = acc0[rr];
            sG[khalf][gRow + rr][gCol0 + 16] = acc1[rr];
        }
        __syncthreads();
        // 5. LSTM cell (fp32), summing the two K-half partials
        {
            float gq[4];
#pragma unroll
            for (int q = 0; q < 4; ++q) {
                int c = q * 8 + r;
                gq[q] = sG[0][b][c] + sG[1][b][c] + bf2f(sXp[b][c]) + bias[q];
            }
            float ig = sigmoidf(gq[0]), fg = sigmoidf(gq[1]);
            float gg = tanh_safe(gq[2]), og = sigmoidf(gq[3]);
            cstate = fg * cstate + ig * gg;
            float h = og * tanh_safe(cstate);
            u16 hh = f2bf(h);
            if (LAYER == 0) {
                out0[((size_t)(b * 512 + tt)) * 1024 + dir * 512 + slice * 8 + r] = hh;
            } else {
                pool += h * (float)mask[b * 512 + tt];
            }
            sHoutHi[b][r] = hh;
            sHoutLo[b][r] = f2bf(h - bf2f(hh));
        }
        __syncthreads();
        // 6. publish h slice (u64 stores, both planes) to IC
        if (tid < 128) {
            int plane = tid >> 6;
            int w = tid & 63, row = w >> 1, half = w & 1;
            u64 v = plane ? ((const u64*)sHoutLo)[w] : ((const u64*)sHoutHi)[w];
            u64* g = (u64*)(hbD + (t & 1) * 32768 + plane * 16384 + row * 512 + slice * 8) + half;
            __hip_atomic_store(g, v, __ATOMIC_RELAXED, __HIP_MEMORY_SCOPE_AGENT);
        }
        __syncthreads();   // vmcnt(0) drain -> h stores complete at IC before flag
        if (tid == 0)
            __hip_atomic_store(myFlags + slice, (u32)(t + 1), __ATOMIC_RELEASE, __HIP_MEMORY_SCOPE_AGENT);
    }
    if (LAYER == 1)
        pooled[(size_t)b * 1024 + dir * 512 + slice * 8 + r] = pool;
}

// ---------- final: logits = (pooled/msum) @ fcW^T + fcb ----------
__global__ __launch_bounds__(256) void final_fc(const float* __restrict__ pooled, const int* __restrict__ mask,
                                                const float* __restrict__ fcW, const float* __restrict__ fcb,
                                                float* __restrict__ out) {
    __shared__ float red[256];
    int tid = threadIdx.x;
    int pair = tid & 63, kc = tid >> 6;
    int b = pair >> 1, c = pair & 1;
    float s = 0.f;
    for (int k = kc * 256; k < kc * 256 + 256; ++k)
        s += pooled[b * 1024 + k] * fcW[c * 1024 + k];
    red[tid] = s;
    __syncthreads();
    if (kc == 0) {
        float tot = red[pair] + red[64 + pair] + red[128 + pair] + red[192 + pair];
        float ms = 0.f;
        for (int t = 0; t < 512; ++t) ms += (float)mask[b * 512 + t];
        ms = fmaxf(ms, 1e-9f);
        out[b * 2 + c] = tot / ms + fcb[c];
    }
}

extern "C" void kernel_launch(void* const* d_in, const int* in_sizes, int n_in,
                              void* d_out, int out_size, void* d_ws, size_t ws_size,
                              hipStream_t stream) {
    (void)in_sizes; (void)n_in; (void)out_size; (void)ws_size;
    const int*   x     = (const int*)d_in[0];
    const int*   amask = (const int*)d_in[1];
    const float* emb   = (const float*)d_in[2];
    const float* fcW   = (const float*)d_in[3];
    const float* fcb   = (const float*)d_in[4];
    const float* fWih0 = (const float*)d_in[5];
    const float* fWhh0 = (const float*)d_in[6];
    const float* fbih0 = (const float*)d_in[7];
    const float* fbhh0 = (const float*)d_in[8];
    const float* bWih0 = (const float*)d_in[9];
    const float* bWhh0 = (const float*)d_in[10];
    const float* bbih0 = (const float*)d_in[11];
    const float* bbhh0 = (const float*)d_in[12];
    const float* fWih1 = (const float*)d_in[13];
    const float* fWhh1 = (const float*)d_in[14];
    const float* fbih1 = (const float*)d_in[15];
    const float* fbhh1 = (const float*)d_in[16];
    const float* bWih1 = (const float*)d_in[17];
    const float* bWhh1 = (const float*)d_in[18];
    const float* bbih1 = (const float*)d_in[19];
    const float* bbhh1 = (const float*)d_in[20];

    char* ws = (char*)d_ws;
    size_t off = 0;
    auto alloc = [&](size_t bytes) { void* p = ws + off; off += (bytes + 1023) & ~(size_t)1023; return p; };
    u16* x0    = (u16*)alloc((size_t)16384 * 512 * 2);
    u16* xpf   = (u16*)alloc((size_t)16384 * 2048 * 2);
    u16* xpb   = (u16*)alloc((size_t)16384 * 2048 * 2);
    u16* out0  = (u16*)alloc((size_t)16384 * 1024 * 2);
    u16* wih0fH = (u16*)alloc((size_t)2048 * 512 * 2);
    u16* wih0fL = (u16*)alloc((size_t)2048 * 512 * 2);
    u16* wih0bH = (u16*)alloc((size_t)2048 * 512 * 2);
    u16* wih0bL = (u16*)alloc((size_t)2048 * 512 * 2);
    u16* whh0fH = (u16*)alloc((size_t)2048 * 512 * 2);
    u16* whh0fL = (u16*)alloc((size_t)2048 * 512 * 2);
    u16* whh0bH = (u16*)alloc((size_t)2048 * 512 * 2);
    u16* whh0bL = (u16*)alloc((size_t)2048 * 512 * 2);
    u16* wih1fH = (u16*)alloc((size_t)2048 * 1024 * 2);
    u16* wih1fL = (u16*)alloc((size_t)2048 * 1024 * 2);
    u16* wih1bH = (u16*)alloc((size_t)2048 * 1024 * 2);
    u16* wih1bL = (u16*)alloc((size_t)2048 * 1024 * 2);
    u16* whh1fH = (u16*)alloc((size_t)2048 * 512 * 2);
    u16* whh1fL = (u16*)alloc((size_t)2048 * 512 * 2);
    u16* whh1bH = (u16*)alloc((size_t)2048 * 512 * 2);
    u16* whh1bL = (u16*)alloc((size_t)2048 * 512 * 2);
    float* pooled = (float*)alloc((size_t)32 * 1024 * 4);
    u16* hbuf  = (u16*)alloc((size_t)2 * 2 * 2 * 32 * 512 * 2);
    u32* flg   = (u32*)alloc(8192);

    hipMemsetAsync(flg, 0, 8192, stream);

    const int NW0 = 2048 * 512, NW1 = 2048 * 1024;
    castk2<<<dim3((NW0 + 255) / 256), 256, 0, stream>>>(fWih0, wih0fH, wih0fL, NW0);
    castk2<<<dim3((NW0 + 255) / 256), 256, 0, stream>>>(bWih0, wih0bH, wih0bL, NW0);
    castk2<<<dim3((NW0 + 255) / 256), 256, 0, stream>>>(fWhh0, whh0fH, whh0fL, NW0);
    castk2<<<dim3((NW0 + 255) / 256), 256, 0, stream>>>(bWhh0, whh0bH, whh0bL, NW0);
    castk2<<<dim3((NW1 + 255) / 256), 256, 0, stream>>>(fWih1, wih1fH, wih1fL, NW1);
    castk2<<<dim3((NW1 + 255) / 256), 256, 0, stream>>>(bWih1, wih1bH, wih1bL, NW1);
    castk2<<<dim3((NW0 + 255) / 256), 256, 0, stream>>>(fWhh1, whh1fH, whh1fL, NW0);
    castk2<<<dim3((NW0 + 255) / 256), 256, 0, stream>>>(bWhh1, whh1bH, whh1bL, NW0);

    embed_cast<<<dim3(16384), 256, 0, stream>>>(x, emb, x0);

    gemm_bt<<<dim3(16, 128), 256, 0, stream>>>(x0, wih0fH, wih0fL, xpf, 16384, 2048, 512);
    gemm_bt<<<dim3(16, 128), 256, 0, stream>>>(x0, wih0bH, wih0bL, xpb, 16384, 2048, 512);
    lstm_rec<0><<<dim3(128), 256, 0, stream>>>(xpf, xpb, whh0fH, whh0fL, whh0bH, whh0bL,
                                               fbih0, fbhh0, bbih0, bbhh0,
                                               out0, nullptr, nullptr, hbuf, flg);
    gemm_bt<<<dim3(16, 128), 256, 0, stream>>>(out0, wih1fH, wih1fL, xpf, 16384, 2048, 1024);
    gemm_bt<<<dim3(16, 128), 256, 0, stream>>>(out0, wih1bH, wih1bL, xpb, 16384, 2048, 1024);
    lstm_rec<1><<<dim3(128), 256, 0, stream>>>(xpf, xpb, whh1fH, whh1fL, whh1bH, whh1bL,
                                               fbih1, fbhh1, bbih1, bbhh1,
                                               nullptr, pooled, amask, hbuf, flg + 256);

    final_fc<<<dim3(1), 256, 0, stream>>>(pooled, amask, fcW, fcb, (float*)d_out);
}